// Round 3
// baseline (60.631 us; speedup 1.0000x reference)
//
#include <hip/hip_runtime.h>
#include <hip/hip_bf16.h>
#include <math.h>

#define D_MODEL 1024
#define LSEQ 2048
#define BATCH 2
#define NROWS (BATCH*LSEQ)   // 4096
#define NACT 8               // active decay chunks (A^256 underflows to 0 for A<0.668)
#define CHSL 32              // decay chunk length

typedef __bf16 bf16;
typedef __attribute__((ext_vector_type(8))) __bf16 bf16x8;
typedef __attribute__((ext_vector_type(4))) __bf16 bf16x4;
typedef __attribute__((ext_vector_type(4))) float f32x4;

__device__ __forceinline__ float sigA(float ap) {
    return fmaxf(1.0f / (1.0f + expf(-ap)), 1e-30f);
}

// async global->LDS, 16B/lane; LDS dest = wave-uniform base + lane*16
__device__ __forceinline__ void gload_lds16(const void* g, void* l) {
    __builtin_amdgcn_global_load_lds(
        (const __attribute__((address_space(1))) void*)g,
        (__attribute__((address_space(3))) void*)l, 16, 0, 0);
}

// ---------------- K1: decay partial sums over 32-long chunks (only first 8 chunks nonzero)
__global__ __launch_bounds__(256) void k_decay(const float* __restrict__ x,
                                               const float* __restrict__ A_param,
                                               float* __restrict__ partial) {
    const int c = blockIdx.x, dg = blockIdx.y, b = blockIdx.z;
    const int d = dg * 256 + threadIdx.x;
    const float A = sigA(A_param[d]);
    const float l2A = log2f(A);
    const int s0 = c * CHSL;
    float w = exp2f((float)s0 * l2A);
    float sum = 0.0f;
    // last active chunk extends to end-of-sequence with early break (safety if A is large)
    const int jmax = (c == NACT - 1) ? (LSEQ - s0) : CHSL;
    if (w != 0.0f) {
        const float* xp = x + ((size_t)b * LSEQ + s0) * D_MODEL + d;
        for (int j0 = 0; j0 < jmax; j0 += 8) {
            if (w == 0.0f) break;
            #pragma unroll
            for (int j = 0; j < 8; ++j) {
                sum += w * xp[(size_t)(j0 + j) * D_MODEL];
                w *= A;
            }
        }
    }
    partial[((size_t)b * NACT + c) * D_MODEL + d] = sum;
}

// ---------------- K2: W f32 -> bf16
__global__ __launch_bounds__(256) void k_wcast(const float* __restrict__ W, bf16* __restrict__ Wb) {
    int idx = (blockIdx.x * 256 + threadIdx.x) * 4;   // D*D = 1M, exact
    f32x4 v = *reinterpret_cast<const f32x4*>(W + idx);
    bf16x4 o;
    #pragma unroll
    for (int k = 0; k < 4; ++k) o[k] = (bf16)v[k];
    *reinterpret_cast<bf16x4*>(Wb + idx) = o;
}

// ---------------- K3: conv closed-form + skip + exact GELU -> bf16 G
__global__ __launch_bounds__(256) void k_prep(const float* __restrict__ x,
                                              const float* __restrict__ A_param,
                                              const float* __restrict__ Bv,
                                              const float* __restrict__ Cv,
                                              const float* __restrict__ Dv,
                                              const float* __restrict__ partial,
                                              bf16* __restrict__ G) {
    const int ib = blockIdx.x, b = blockIdx.z;   // grid (LSEQ/16, 1, BATCH)
    const int i0 = ib * 16;
    const int d0 = threadIdx.x * 4;              // 256*4 = 1024 = D
    f32x4 P = {0.f, 0.f, 0.f, 0.f};
    #pragma unroll
    for (int c = 0; c < NACT; ++c)
        P += *reinterpret_cast<const f32x4*>(partial + ((size_t)b * NACT + c) * D_MODEL + d0);
    float A4[4], coeff[4], dvv[4], w[4];
    #pragma unroll
    for (int k = 0; k < 4; ++k) {
        A4[k] = sigA(A_param[d0 + k]);
        float l2 = log2f(A4[k]);
        coeff[k] = Cv[d0 + k] * Bv[d0 + k] * P[k];
        dvv[k] = Dv[d0 + k];
        w[k] = exp2f((float)(LSEQ - 1 - (i0 + 15)) * l2);   // conv(i) = coeff * A^(L-1-i)
    }
    for (int j = 15; j >= 0; --j) {
        const int i = i0 + j;
        f32x4 xv = *reinterpret_cast<const f32x4*>(x + ((size_t)b * LSEQ + i) * D_MODEL + d0);
        bf16x4 g;
        #pragma unroll
        for (int k = 0; k < 4; ++k) {
            float u = coeff[k] * w[k] + dvv[k] * xv[k];
            g[k] = (bf16)(0.5f * u * (1.0f + erff(u * 0.70710678118654752f)));
            w[k] *= A4[k];
        }
        *reinterpret_cast<bf16x4*>(G + ((size_t)b * LSEQ + i) * D_MODEL + d0) = g;
    }
}

// ---------------- K4: Z = bf16(x + G @ Wb^T + bias)
// TM=TN=128, BK=64, 4 waves (2x2), wave tile 64x64.
// FRAGMENT-ORDERED LDS: 32 regions x 1KB per buffer; region holds one wave-fragment
// in lane order -> every ds_read_b128 is region_base + lane*16 (zero bank conflicts).
// Staging pre-gathers fragments via per-lane global addresses (gload_lds dest stays linear).
__global__ __launch_bounds__(256, 1) void k_gemm(const bf16* __restrict__ G,
                                                 const bf16* __restrict__ Wb,
                                                 const float* __restrict__ bias,
                                                 const float* __restrict__ x,
                                                 bf16* __restrict__ Z) {
    __shared__ __align__(16) bf16 S[2][32 * 512];   // 2 x 32KB
    const int tid = threadIdx.x;
    const int lane = tid & 63, wave = tid >> 6;
    const int row0 = blockIdx.x * 128, col0 = blockIdx.y * 128;
    const int wr = wave >> 1, wc = wave & 1;        // wave tile 64x64
    const int fr = lane & 15;                       // fragment row/col within 16
    const int fk = (lane >> 4) * 8;                 // k-offset within 32-slice
    f32x4 acc[4][4] = {};

    // this wave's 8 staging regions: rid = wave*8 + r
    // rid 0..15 : A region (wr=rid>>3, fm=(rid>>1)&3, ks=rid&1)
    // rid 16..31: B region (wc, fn, ks) same decomposition
    const bf16* srcbase[8];
    #pragma unroll
    for (int r = 0; r < 8; ++r) {
        const int rid = wave * 8 + r;
        const int isB = rid >> 4;
        const int rr = rid & 15;
        const int grow = (isB ? col0 : row0) + (rr >> 3) * 64 + ((rr >> 1) & 3) * 16 + fr;
        const int gcol = (rr & 1) * 32 + fk;
        srcbase[r] = (isB ? Wb : G) + (size_t)grow * D_MODEL + gcol;
    }

    auto stage = [&](int buf, int k0) {
        #pragma unroll
        for (int r = 0; r < 8; ++r)
            gload_lds16(srcbase[r] + k0, &S[buf][(wave * 8 + r) * 512]);
    };

    stage(0, 0);
    __syncthreads();
    for (int t = 0; t < 16; ++t) {
        const int cur = t & 1;
        if (t < 15) stage(cur ^ 1, (t + 1) * 64);
        const bf16* SA = &S[cur][(wr * 8) * 512];
        const bf16* SB = &S[cur][(16 + wc * 8) * 512];
        bf16x8 a[4][2], bb[4][2];
        #pragma unroll
        for (int fm = 0; fm < 4; ++fm)
            #pragma unroll
            for (int ks = 0; ks < 2; ++ks)
                a[fm][ks] = *reinterpret_cast<const bf16x8*>(SA + (fm * 2 + ks) * 512 + lane * 8);
        #pragma unroll
        for (int fn = 0; fn < 4; ++fn)
            #pragma unroll
            for (int ks = 0; ks < 2; ++ks)
                bb[fn][ks] = *reinterpret_cast<const bf16x8*>(SB + (fn * 2 + ks) * 512 + lane * 8);
        #pragma unroll
        for (int fm = 0; fm < 4; ++fm)
            #pragma unroll
            for (int fn = 0; fn < 4; ++fn)
                #pragma unroll
                for (int ks = 0; ks < 2; ++ks)
                    acc[fm][fn] = __builtin_amdgcn_mfma_f32_16x16x32_bf16(a[fm][ks], bb[fn][ks], acc[fm][fn], 0, 0, 0);
        __syncthreads();
    }
    // epilogue: C/D layout col = lane&15, row = (lane>>4)*4 + reg; fuse +bias +x, emit bf16
    #pragma unroll
    for (int fm = 0; fm < 4; ++fm) {
        const int rbase = row0 + wr * 64 + fm * 16 + (lane >> 4) * 4;
        #pragma unroll
        for (int fn = 0; fn < 4; ++fn) {
            const int c = col0 + wc * 64 + fn * 16 + fr;
            const float bv = bias[c];
            #pragma unroll
            for (int r = 0; r < 4; ++r) {
                const int rr = rbase + r;
                float z = acc[fm][fn][r] + bv + x[(size_t)rr * D_MODEL + c];
                Z[(size_t)rr * D_MODEL + c] = (bf16)z;
            }
        }
    }
}

// ---------------- K5: out = LayerNorm(Z) * gamma + beta
__global__ __launch_bounds__(256) void k_ln(const bf16* __restrict__ Z,
                                            const float* __restrict__ gamma,
                                            const float* __restrict__ beta,
                                            float* __restrict__ out) {
    const int row = blockIdx.x;
    const int t = threadIdx.x;
    bf16x4 zv = *reinterpret_cast<const bf16x4*>(Z + (size_t)row * D_MODEL + t * 4);
    float z[4];
    float s = 0.0f, sq = 0.0f;
    #pragma unroll
    for (int k = 0; k < 4; ++k) {
        z[k] = (float)zv[k];
        s += z[k]; sq += z[k] * z[k];
    }
    #pragma unroll
    for (int o = 1; o < 64; o <<= 1) { s += __shfl_xor(s, o, 64); sq += __shfl_xor(sq, o, 64); }
    __shared__ float ls[4], lq[4];
    const int wave = t >> 6;
    if ((t & 63) == 0) { ls[wave] = s; lq[wave] = sq; }
    __syncthreads();
    s = ls[0] + ls[1] + ls[2] + ls[3];
    sq = lq[0] + lq[1] + lq[2] + lq[3];
    const float mu = s * (1.0f / D_MODEL);
    const float var = sq * (1.0f / D_MODEL) - mu * mu;
    const float inv = rsqrtf(var + 1e-5f);
    f32x4 g = *reinterpret_cast<const f32x4*>(gamma + t * 4);
    f32x4 be = *reinterpret_cast<const f32x4*>(beta + t * 4);
    f32x4 o;
    #pragma unroll
    for (int k = 0; k < 4; ++k) o[k] = (z[k] - mu) * inv * g[k] + be[k];
    *reinterpret_cast<f32x4*>(out + (size_t)row * D_MODEL + t * 4) = o;
}

extern "C" void kernel_launch(void* const* d_in, const int* in_sizes, int n_in,
                              void* d_out, int out_size, void* d_ws, size_t ws_size,
                              hipStream_t stream) {
    const float* x       = (const float*)d_in[0];
    const float* A_param = (const float*)d_in[1];
    const float* B_vec   = (const float*)d_in[2];
    const float* C_vec   = (const float*)d_in[3];
    const float* D_vec   = (const float*)d_in[4];
    const float* W       = (const float*)d_in[5];
    const float* b_proj  = (const float*)d_in[6];
    const float* gamma   = (const float*)d_in[7];
    const float* beta    = (const float*)d_in[8];
    float* out = (float*)d_out;

    char* ws = (char*)d_ws;
    float* partial = (float*)ws;                                  // 2*8*1024*4 = 64 KiB
    bf16*  Wb      = (bf16*)(ws + (128 << 10));                   // 2 MiB
    bf16*  G       = (bf16*)(ws + (128 << 10) + (2 << 20));       // 8 MiB
    bf16*  Z       = (bf16*)(ws + (128 << 10) + (10 << 20));      // 8 MiB

    hipLaunchKernelGGL(k_decay, dim3(NACT, D_MODEL / 256, BATCH), dim3(256), 0, stream, x, A_param, partial);
    hipLaunchKernelGGL(k_wcast, dim3(D_MODEL * D_MODEL / 1024), dim3(256), 0, stream, W, Wb);
    hipLaunchKernelGGL(k_prep,  dim3(LSEQ / 16, 1, BATCH), dim3(256), 0, stream,
                       x, A_param, B_vec, C_vec, D_vec, partial, G);
    hipLaunchKernelGGL(k_gemm,  dim3(NROWS / 128, D_MODEL / 128), dim3(256), 0, stream, G, Wb, b_proj, x, Z);
    hipLaunchKernelGGL(k_ln,    dim3(NROWS), dim3(256), 0, stream, Z, gamma, beta, out);
}

// Round 4
// 59.832 us; speedup vs baseline: 1.0134x; 1.0134x over previous
//
#include <hip/hip_runtime.h>
#include <hip/hip_bf16.h>
#include <math.h>

#define D_MODEL 1024
#define LSEQ 2048
#define BATCH 2
#define NROWS (BATCH*LSEQ)   // 4096
#define NACT 8               // active decay chunks (A^256 underflows to 0 for observed A)
#define CHSL 32              // decay chunk length

typedef __bf16 bf16;
typedef __attribute__((ext_vector_type(8))) __bf16 bf16x8;
typedef __attribute__((ext_vector_type(4))) __bf16 bf16x4;
typedef __attribute__((ext_vector_type(4))) float f32x4;

__device__ __forceinline__ float sigA(float ap) {
    return fmaxf(1.0f / (1.0f + expf(-ap)), 1e-30f);
}

// async global->LDS, 16B/lane; LDS dest = wave-uniform base + lane*16
__device__ __forceinline__ void gload_lds16(const void* g, void* l) {
    __builtin_amdgcn_global_load_lds(
        (const __attribute__((address_space(1))) void*)g,
        (__attribute__((address_space(3))) void*)l, 16, 0, 0);
}

// ---------------- K1: decay partial sums over 32-long chunks (only first 8 chunks nonzero)
__global__ __launch_bounds__(256) void k_decay(const float* __restrict__ x,
                                               const float* __restrict__ A_param,
                                               float* __restrict__ partial) {
    const int c = blockIdx.x, dg = blockIdx.y, b = blockIdx.z;
    const int d = dg * 256 + threadIdx.x;
    const float A = sigA(A_param[d]);
    const float l2A = log2f(A);
    const int s0 = c * CHSL;
    float w = exp2f((float)s0 * l2A);
    float sum = 0.0f;
    // last active chunk extends to end-of-sequence with early break (safety if A is large)
    const int jmax = (c == NACT - 1) ? (LSEQ - s0) : CHSL;
    if (w != 0.0f) {
        const float* xp = x + ((size_t)b * LSEQ + s0) * D_MODEL + d;
        for (int j0 = 0; j0 < jmax; j0 += 8) {
            if (w == 0.0f) break;
            #pragma unroll
            for (int j = 0; j < 8; ++j) {
                sum += w * xp[(size_t)(j0 + j) * D_MODEL];
                w *= A;
            }
        }
    }
    partial[((size_t)b * NACT + c) * D_MODEL + d] = sum;
}

// ---------------- K2: W f32 -> bf16
__global__ __launch_bounds__(256) void k_wcast(const float* __restrict__ W, bf16* __restrict__ Wb) {
    int idx = (blockIdx.x * 256 + threadIdx.x) * 4;   // D*D = 1M, exact
    f32x4 v = *reinterpret_cast<const f32x4*>(W + idx);
    bf16x4 o;
    #pragma unroll
    for (int k = 0; k < 4; ++k) o[k] = (bf16)v[k];
    *reinterpret_cast<bf16x4*>(Wb + idx) = o;
}

// ---------------- K3: conv closed-form + skip + exact GELU -> bf16 G
__global__ __launch_bounds__(256) void k_prep(const float* __restrict__ x,
                                              const float* __restrict__ A_param,
                                              const float* __restrict__ Bv,
                                              const float* __restrict__ Cv,
                                              const float* __restrict__ Dv,
                                              const float* __restrict__ partial,
                                              bf16* __restrict__ G) {
    const int ib = blockIdx.x, b = blockIdx.z;   // grid (LSEQ/16, 1, BATCH)
    const int i0 = ib * 16;
    const int d0 = threadIdx.x * 4;              // 256*4 = 1024 = D
    f32x4 P = {0.f, 0.f, 0.f, 0.f};
    #pragma unroll
    for (int c = 0; c < NACT; ++c)
        P += *reinterpret_cast<const f32x4*>(partial + ((size_t)b * NACT + c) * D_MODEL + d0);
    float A4[4], coeff[4], dvv[4], w[4];
    #pragma unroll
    for (int k = 0; k < 4; ++k) {
        A4[k] = sigA(A_param[d0 + k]);
        float l2 = log2f(A4[k]);
        coeff[k] = Cv[d0 + k] * Bv[d0 + k] * P[k];
        dvv[k] = Dv[d0 + k];
        w[k] = exp2f((float)(LSEQ - 1 - (i0 + 15)) * l2);   // conv(i) = coeff * A^(L-1-i)
    }
    for (int j = 15; j >= 0; --j) {
        const int i = i0 + j;
        f32x4 xv = *reinterpret_cast<const f32x4*>(x + ((size_t)b * LSEQ + i) * D_MODEL + d0);
        bf16x4 g;
        #pragma unroll
        for (int k = 0; k < 4; ++k) {
            float u = coeff[k] * w[k] + dvv[k] * xv[k];
            g[k] = (bf16)(0.5f * u * (1.0f + erff(u * 0.70710678118654752f)));
            w[k] *= A4[k];
        }
        *reinterpret_cast<bf16x4*>(G + ((size_t)b * LSEQ + i) * D_MODEL + d0) = g;
    }
}

// ---------------- K4: Z = bf16(x + G @ Wb^T + bias)
// TM=64 TN=128 BK=64, 4 waves (2x2), wave tile 32x64, grid 512 blocks (2-3/CU).
// FRAGMENT-ORDERED LDS: 24 regions x 1KB per buffer; a region is one MFMA fragment
// in lane order -> every ds_read_b128 is region_base + lane*16 (conflict-free by
// construction). Staging pre-gathers via per-lane global addrs; gload_lds dest linear.
// XCD-chunked swizzle: x = (bid%8)*8 + (bid/8)%8, y = bid/64 -> each XCD keeps its
// 8 G row-panels (1MB) + Wb (2MB) L2-resident.
__global__ __launch_bounds__(256) void k_gemm(const bf16* __restrict__ G,
                                              const bf16* __restrict__ Wb,
                                              const float* __restrict__ bias,
                                              const float* __restrict__ x,
                                              bf16* __restrict__ Z) {
    __shared__ __align__(16) bf16 S[2][24 * 512];   // 2 x 24KB
    const int tid = threadIdx.x;
    const int lane = tid & 63, wave = tid >> 6;
    const int bid = blockIdx.x;
    const int bx = (bid & 7) * 8 + ((bid >> 3) & 7);   // m-tile [0,64)
    const int by = bid >> 6;                           // n-tile [0,8)
    const int row0 = bx * 64, col0 = by * 128;
    const int wr = wave >> 1, wc = wave & 1;      // wave tile 32x64
    const int fr = lane & 15;                     // row within 16-fragment
    const int fk = (lane >> 4) * 8;               // k-offset within 32-slice
    f32x4 acc[2][4] = {};

    // regions: rid 0..7  = A (wr, fm, ks): rid = wr*4 + fm*2 + ks
    //          rid 8..23 = B (wc, fn, ks): rid = 8 + wc*8 + fn*2 + ks
    // wave stages rids [wave*6, wave*6+6)
    const bf16* srcbase[6];
    #pragma unroll
    for (int r = 0; r < 6; ++r) {
        const int rid = wave * 6 + r;
        int grow, gcol;
        const bf16* mat;
        if (rid < 8) {
            grow = row0 + (rid >> 2) * 32 + ((rid >> 1) & 1) * 16 + fr;
            gcol = (rid & 1) * 32 + fk;
            mat = G;
        } else {
            const int rr = rid - 8;
            grow = col0 + (rr >> 3) * 64 + ((rr >> 1) & 3) * 16 + fr;
            gcol = (rr & 1) * 32 + fk;
            mat = Wb;
        }
        srcbase[r] = mat + (size_t)grow * D_MODEL + gcol;
    }

    auto stage = [&](int buf, int k0) {
        #pragma unroll
        for (int r = 0; r < 6; ++r)
            gload_lds16(srcbase[r] + k0, &S[buf][(wave * 6 + r) * 512]);
    };

    stage(0, 0);
    __syncthreads();
    for (int t = 0; t < 16; ++t) {
        const int cur = t & 1;
        if (t < 15) stage(cur ^ 1, (t + 1) * 64);
        bf16x8 a[2][2], bb[4][2];
        #pragma unroll
        for (int fm = 0; fm < 2; ++fm)
            #pragma unroll
            for (int ks = 0; ks < 2; ++ks)
                a[fm][ks] = *reinterpret_cast<const bf16x8*>(&S[cur][(wr * 4 + fm * 2 + ks) * 512 + lane * 8]);
        #pragma unroll
        for (int fn = 0; fn < 4; ++fn)
            #pragma unroll
            for (int ks = 0; ks < 2; ++ks)
                bb[fn][ks] = *reinterpret_cast<const bf16x8*>(&S[cur][(8 + wc * 8 + fn * 2 + ks) * 512 + lane * 8]);
        #pragma unroll
        for (int fm = 0; fm < 2; ++fm)
            #pragma unroll
            for (int fn = 0; fn < 4; ++fn)
                #pragma unroll
                for (int ks = 0; ks < 2; ++ks)
                    acc[fm][fn] = __builtin_amdgcn_mfma_f32_16x16x32_bf16(a[fm][ks], bb[fn][ks], acc[fm][fn], 0, 0, 0);
        __syncthreads();
    }
    // epilogue: C/D layout col = lane&15, row = (lane>>4)*4 + reg; fuse +bias +x, emit bf16
    #pragma unroll
    for (int fm = 0; fm < 2; ++fm) {
        const int rbase = row0 + wr * 32 + fm * 16 + (lane >> 4) * 4;
        #pragma unroll
        for (int fn = 0; fn < 4; ++fn) {
            const int c = col0 + wc * 64 + fn * 16 + fr;
            const float bv = bias[c];
            #pragma unroll
            for (int r = 0; r < 4; ++r) {
                const int rr = rbase + r;
                float z = acc[fm][fn][r] + bv + x[(size_t)rr * D_MODEL + c];
                Z[(size_t)rr * D_MODEL + c] = (bf16)z;
            }
        }
    }
}

// ---------------- K5: out = LayerNorm(Z) * gamma + beta
__global__ __launch_bounds__(256) void k_ln(const bf16* __restrict__ Z,
                                            const float* __restrict__ gamma,
                                            const float* __restrict__ beta,
                                            float* __restrict__ out) {
    const int row = blockIdx.x;
    const int t = threadIdx.x;
    bf16x4 zv = *reinterpret_cast<const bf16x4*>(Z + (size_t)row * D_MODEL + t * 4);
    float z[4];
    float s = 0.0f, sq = 0.0f;
    #pragma unroll
    for (int k = 0; k < 4; ++k) {
        z[k] = (float)zv[k];
        s += z[k]; sq += z[k] * z[k];
    }
    #pragma unroll
    for (int o = 1; o < 64; o <<= 1) { s += __shfl_xor(s, o, 64); sq += __shfl_xor(sq, o, 64); }
    __shared__ float ls[4], lq[4];
    const int wave = t >> 6;
    if ((t & 63) == 0) { ls[wave] = s; lq[wave] = sq; }
    __syncthreads();
    s = ls[0] + ls[1] + ls[2] + ls[3];
    sq = lq[0] + lq[1] + lq[2] + lq[3];
    const float mu = s * (1.0f / D_MODEL);
    const float var = sq * (1.0f / D_MODEL) - mu * mu;
    const float inv = rsqrtf(var + 1e-5f);
    f32x4 g = *reinterpret_cast<const f32x4*>(gamma + t * 4);
    f32x4 be = *reinterpret_cast<const f32x4*>(beta + t * 4);
    f32x4 o;
    #pragma unroll
    for (int k = 0; k < 4; ++k) o[k] = (z[k] - mu) * inv * g[k] + be[k];
    *reinterpret_cast<f32x4*>(out + (size_t)row * D_MODEL + t * 4) = o;
}

extern "C" void kernel_launch(void* const* d_in, const int* in_sizes, int n_in,
                              void* d_out, int out_size, void* d_ws, size_t ws_size,
                              hipStream_t stream) {
    const float* x       = (const float*)d_in[0];
    const float* A_param = (const float*)d_in[1];
    const float* B_vec   = (const float*)d_in[2];
    const float* C_vec   = (const float*)d_in[3];
    const float* D_vec   = (const float*)d_in[4];
    const float* W       = (const float*)d_in[5];
    const float* b_proj  = (const float*)d_in[6];
    const float* gamma   = (const float*)d_in[7];
    const float* beta    = (const float*)d_in[8];
    float* out = (float*)d_out;

    char* ws = (char*)d_ws;
    float* partial = (float*)ws;                                  // 64 KiB
    bf16*  Wb      = (bf16*)(ws + (128 << 10));                   // 2 MiB
    bf16*  G       = (bf16*)(ws + (128 << 10) + (2 << 20));       // 8 MiB
    bf16*  Z       = (bf16*)(ws + (128 << 10) + (10 << 20));      // 8 MiB

    hipLaunchKernelGGL(k_decay, dim3(NACT, D_MODEL / 256, BATCH), dim3(256), 0, stream, x, A_param, partial);
    hipLaunchKernelGGL(k_wcast, dim3(D_MODEL * D_MODEL / 1024), dim3(256), 0, stream, W, Wb);
    hipLaunchKernelGGL(k_prep,  dim3(LSEQ / 16, 1, BATCH), dim3(256), 0, stream,
                       x, A_param, B_vec, C_vec, D_vec, partial, G);
    hipLaunchKernelGGL(k_gemm,  dim3(512), dim3(256), 0, stream, G, Wb, b_proj, x, Z);
    hipLaunchKernelGGL(k_ln,    dim3(NROWS), dim3(256), 0, stream, Z, gamma, beta, out);
}

// Round 5
// 41.298 us; speedup vs baseline: 1.4681x; 1.4488x over previous
//
#include <hip/hip_runtime.h>
#include <hip/hip_bf16.h>
#include <math.h>

#define D_MODEL 1024
#define LSEQ 2048
#define BATCH 2
#define NROWS (BATCH*LSEQ)   // 4096
#define NACT 8               // active decay chunks (A^256 underflows to 0 for observed A)
#define CHSL 32              // decay chunk length

typedef __bf16 bf16;
typedef __attribute__((ext_vector_type(8))) __bf16 bf16x8;
typedef __attribute__((ext_vector_type(4))) __bf16 bf16x4;
typedef __attribute__((ext_vector_type(4))) float f32x4;

__device__ __forceinline__ float sigA(float ap) {
    return fmaxf(1.0f / (1.0f + expf(-ap)), 1e-30f);
}

// async global->LDS, 16B/lane; LDS dest = wave-uniform base + lane*16
__device__ __forceinline__ void gload_lds16(const void* g, void* l) {
    __builtin_amdgcn_global_load_lds(
        (const __attribute__((address_space(1))) void*)g,
        (__attribute__((address_space(3))) void*)l, 16, 0, 0);
}

// ---------------- K1: merged W-cast (blocks 0..1023) + decay partial sums (blocks 1024..1087)
__global__ __launch_bounds__(256) void k_misc(const float* __restrict__ W, bf16* __restrict__ Wb,
                                              const float* __restrict__ x,
                                              const float* __restrict__ A_param,
                                              float* __restrict__ partial) {
    if (blockIdx.x < 1024) {                     // W f32 -> bf16
        int idx = (blockIdx.x * 256 + threadIdx.x) * 4;   // D*D = 1M
        f32x4 v = *reinterpret_cast<const f32x4*>(W + idx);
        bf16x4 o;
        #pragma unroll
        for (int k = 0; k < 4; ++k) o[k] = (bf16)v[k];
        *reinterpret_cast<bf16x4*>(Wb + idx) = o;
        return;
    }
    const int flat = blockIdx.x - 1024;          // 0..63
    const int c = flat & 7, dg = (flat >> 3) & 3, b = flat >> 5;
    const int d = dg * 256 + threadIdx.x;
    const float A = sigA(A_param[d]);
    const float l2A = log2f(A);
    const int s0 = c * CHSL;
    float w = exp2f((float)s0 * l2A);
    float sum = 0.0f;
    const int jmax = (c == NACT - 1) ? (LSEQ - s0) : CHSL;  // last chunk extends (safety for large A)
    if (w != 0.0f) {
        const float* xp = x + ((size_t)b * LSEQ + s0) * D_MODEL + d;
        for (int j0 = 0; j0 < jmax; j0 += 8) {
            if (w == 0.0f) break;
            #pragma unroll
            for (int j = 0; j < 8; ++j) {
                sum += w * xp[(size_t)(j0 + j) * D_MODEL];
                w *= A;
            }
        }
    }
    partial[((size_t)b * NACT + c) * D_MODEL + d] = sum;
}

// ---------------- K2: conv closed-form + skip + exact GELU -> bf16 G
__global__ __launch_bounds__(256) void k_prep(const float* __restrict__ x,
                                              const float* __restrict__ A_param,
                                              const float* __restrict__ Bv,
                                              const float* __restrict__ Cv,
                                              const float* __restrict__ Dv,
                                              const float* __restrict__ partial,
                                              bf16* __restrict__ G) {
    const int ib = blockIdx.x, b = blockIdx.z;   // grid (LSEQ/8, 1, BATCH) = 512 blocks
    const int i0 = ib * 8;
    const int d0 = threadIdx.x * 4;              // 256*4 = 1024 = D
    f32x4 P = {0.f, 0.f, 0.f, 0.f};
    #pragma unroll
    for (int c = 0; c < NACT; ++c)
        P += *reinterpret_cast<const f32x4*>(partial + ((size_t)b * NACT + c) * D_MODEL + d0);
    float A4[4], coeff[4], dvv[4], w[4];
    #pragma unroll
    for (int k = 0; k < 4; ++k) {
        A4[k] = sigA(A_param[d0 + k]);
        float l2 = log2f(A4[k]);
        coeff[k] = Cv[d0 + k] * Bv[d0 + k] * P[k];
        dvv[k] = Dv[d0 + k];
        w[k] = exp2f((float)(LSEQ - 1 - (i0 + 7)) * l2);   // conv(i) = coeff * A^(L-1-i)
    }
    for (int j = 7; j >= 0; --j) {
        const int i = i0 + j;
        f32x4 xv = *reinterpret_cast<const f32x4*>(x + ((size_t)b * LSEQ + i) * D_MODEL + d0);
        bf16x4 g;
        #pragma unroll
        for (int k = 0; k < 4; ++k) {
            float u = coeff[k] * w[k] + dvv[k] * xv[k];
            g[k] = (bf16)(0.5f * u * (1.0f + erff(u * 0.70710678118654752f)));
            w[k] *= A4[k];
        }
        *reinterpret_cast<bf16x4*>(G + ((size_t)b * LSEQ + i) * D_MODEL + d0) = g;
    }
}

// ---------------- K3: Z = bf16(G @ Wb^T + bias)
// TM=64 TN=128 BK=64, 4 waves (wave tile 32x64), 512 blocks.
// LDS: 3 buffers x 24KB (A[64][64] + B[128][64] bf16), linear gload_lds dest.
// XOR swizzle WITHIN each 128B row (involution): staging source byte-in-row
// 16*((lane&7)^(lane>>3)) keeps each 8-lane row-group on the same contiguous
// 128B (coalescing preserved); reads use elem 8*((4ks+q)^(fr&7)) -> each
// 8-lane phase hits 8 distinct bank-quads (conflict-free).
// Counted vmcnt (never 0 in steady state): depth-2 prefetch, 6 loads/wave/stage
// -> s_waitcnt vmcnt(12) certifies tile t complete with t+1,t+2 in flight.
__global__ __launch_bounds__(256) void k_gemm(const bf16* __restrict__ G,
                                              const bf16* __restrict__ Wb,
                                              const float* __restrict__ bias,
                                              bf16* __restrict__ Z) {
    __shared__ __align__(16) bf16 S[3 * 12288];   // 3 x 24KB = 72KB
    const int tid = threadIdx.x;
    const int lane = tid & 63, wave = tid >> 6;
    const int bid = blockIdx.x;
    const int bx = (bid & 7) * 8 + ((bid >> 3) & 7);   // m-tile [0,64): XCD-chunked
    const int by = bid >> 6;                           // n-tile [0,8)
    const int row0 = bx * 64, col0 = by * 128;
    const int wr = wave >> 1, wc = wave & 1;      // wave tile 32x64
    const int fr = lane & 15, q = lane >> 4;
    const int fx = fr & 7;
    f32x4 acc[2][4] = {};

    // staging: 24 chunks of 1KB; chunk c covers combined-tile rows [c*8, c*8+8)
    // (rows 0..63 = A from G, 64..191 = B from Wb); wave owns chunks wave*6 .. +6
    const int lr8 = lane >> 3;
    const int sb = 16 * ((lane & 7) ^ lr8);       // swizzled source byte-in-row
    const bf16* srcbase[6];
    #pragma unroll
    for (int r = 0; r < 6; ++r) {
        const int c = wave * 6 + r;
        const bf16* mat;
        int row;
        if (c < 8) { mat = G;  row = row0 + c * 8 + lr8; }
        else       { mat = Wb; row = col0 + (c - 8) * 8 + lr8; }
        srcbase[r] = (const bf16*)((const char*)(mat + (size_t)row * D_MODEL) + sb);
    }

    auto stage = [&](int buf, int k0) {
        #pragma unroll
        for (int r = 0; r < 6; ++r)
            gload_lds16(srcbase[r] + k0, &S[buf * 12288 + (wave * 6 + r) * 512]);
    };

    stage(0, 0);
    stage(1, 64);
    for (int t = 0; t < 16; ++t) {
        const int cur = t % 3;
        if (t + 2 < 16) stage((t + 2) % 3, (t + 2) * 64);
        __builtin_amdgcn_sched_barrier(0);
        if (t < 14)       asm volatile("s_waitcnt vmcnt(12)" ::: "memory");
        else if (t == 14) asm volatile("s_waitcnt vmcnt(6)"  ::: "memory");
        else              asm volatile("s_waitcnt vmcnt(0)"  ::: "memory");
        __builtin_amdgcn_s_barrier();
        __builtin_amdgcn_sched_barrier(0);
        const bf16* SA = &S[cur * 12288];
        const bf16* SB = SA + 4096;
        bf16x8 a[2][2], bb[4][2];
        #pragma unroll
        for (int fm = 0; fm < 2; ++fm)
            #pragma unroll
            for (int ks = 0; ks < 2; ++ks)
                a[fm][ks] = *reinterpret_cast<const bf16x8*>(
                    SA + (wr * 32 + fm * 16 + fr) * 64 + 8 * ((4 * ks + q) ^ fx));
        #pragma unroll
        for (int fn = 0; fn < 4; ++fn)
            #pragma unroll
            for (int ks = 0; ks < 2; ++ks)
                bb[fn][ks] = *reinterpret_cast<const bf16x8*>(
                    SB + (wc * 64 + fn * 16 + fr) * 64 + 8 * ((4 * ks + q) ^ fx));
        #pragma unroll
        for (int fm = 0; fm < 2; ++fm)
            #pragma unroll
            for (int fn = 0; fn < 4; ++fn)
                #pragma unroll
                for (int ks = 0; ks < 2; ++ks)
                    acc[fm][fn] = __builtin_amdgcn_mfma_f32_16x16x32_bf16(a[fm][ks], bb[fn][ks], acc[fm][fn], 0, 0, 0);
        __builtin_amdgcn_sched_barrier(0);
        __builtin_amdgcn_s_barrier();   // reads of buf t done before it is restaged
    }
    // epilogue: C/D layout col = lane&15, row = (lane>>4)*4 + reg; +bias, emit bf16
    #pragma unroll
    for (int fm = 0; fm < 2; ++fm) {
        const int rbase = row0 + wr * 32 + fm * 16 + (lane >> 4) * 4;
        #pragma unroll
        for (int fn = 0; fn < 4; ++fn) {
            const int c = col0 + wc * 64 + fn * 16 + fr;
            const float bv = bias[c];
            #pragma unroll
            for (int r = 0; r < 4; ++r)
                Z[(size_t)(rbase + r) * D_MODEL + c] = (bf16)(acc[fm][fn][r] + bv);
        }
    }
}

// ---------------- K4: out = LayerNorm(x + Z) * gamma + beta
__global__ __launch_bounds__(256) void k_ln(const bf16* __restrict__ Z,
                                            const float* __restrict__ x,
                                            const float* __restrict__ gamma,
                                            const float* __restrict__ beta,
                                            float* __restrict__ out) {
    const int row = blockIdx.x;
    const int t = threadIdx.x;
    bf16x4 zv = *reinterpret_cast<const bf16x4*>(Z + (size_t)row * D_MODEL + t * 4);
    f32x4 xv = *reinterpret_cast<const f32x4*>(x + (size_t)row * D_MODEL + t * 4);
    float z[4];
    float s = 0.0f, sq = 0.0f;
    #pragma unroll
    for (int k = 0; k < 4; ++k) {
        z[k] = xv[k] + (float)zv[k];
        s += z[k]; sq += z[k] * z[k];
    }
    #pragma unroll
    for (int o = 1; o < 64; o <<= 1) { s += __shfl_xor(s, o, 64); sq += __shfl_xor(sq, o, 64); }
    __shared__ float ls[4], lq[4];
    const int wave = t >> 6;
    if ((t & 63) == 0) { ls[wave] = s; lq[wave] = sq; }
    __syncthreads();
    s = ls[0] + ls[1] + ls[2] + ls[3];
    sq = lq[0] + lq[1] + lq[2] + lq[3];
    const float mu = s * (1.0f / D_MODEL);
    const float var = sq * (1.0f / D_MODEL) - mu * mu;
    const float inv = rsqrtf(var + 1e-5f);
    f32x4 g = *reinterpret_cast<const f32x4*>(gamma + t * 4);
    f32x4 be = *reinterpret_cast<const f32x4*>(beta + t * 4);
    f32x4 o;
    #pragma unroll
    for (int k = 0; k < 4; ++k) o[k] = (z[k] - mu) * inv * g[k] + be[k];
    *reinterpret_cast<f32x4*>(out + (size_t)row * D_MODEL + t * 4) = o;
}

extern "C" void kernel_launch(void* const* d_in, const int* in_sizes, int n_in,
                              void* d_out, int out_size, void* d_ws, size_t ws_size,
                              hipStream_t stream) {
    const float* x       = (const float*)d_in[0];
    const float* A_param = (const float*)d_in[1];
    const float* B_vec   = (const float*)d_in[2];
    const float* C_vec   = (const float*)d_in[3];
    const float* D_vec   = (const float*)d_in[4];
    const float* W       = (const float*)d_in[5];
    const float* b_proj  = (const float*)d_in[6];
    const float* gamma   = (const float*)d_in[7];
    const float* beta    = (const float*)d_in[8];
    float* out = (float*)d_out;

    char* ws = (char*)d_ws;
    float* partial = (float*)ws;                                  // 64 KiB
    bf16*  Wb      = (bf16*)(ws + (128 << 10));                   // 2 MiB
    bf16*  G       = (bf16*)(ws + (128 << 10) + (2 << 20));       // 8 MiB
    bf16*  Z       = (bf16*)(ws + (128 << 10) + (10 << 20));      // 8 MiB

    hipLaunchKernelGGL(k_misc, dim3(1088), dim3(256), 0, stream, W, Wb, x, A_param, partial);
    hipLaunchKernelGGL(k_prep, dim3(LSEQ / 8, 1, BATCH), dim3(256), 0, stream,
                       x, A_param, B_vec, C_vec, D_vec, partial, G);
    hipLaunchKernelGGL(k_gemm, dim3(512), dim3(256), 0, stream, G, Wb, b_proj, Z);
    hipLaunchKernelGGL(k_ln,   dim3(NROWS), dim3(256), 0, stream, Z, x, gamma, beta, out);
}